// Round 11
// baseline (284.813 us; speedup 1.0000x reference)
//
#include <hip/hip_runtime.h>
#include <hip/hip_bf16.h>

typedef __attribute__((ext_vector_type(8))) short short8;
typedef __attribute__((ext_vector_type(4))) short short4v;
typedef __attribute__((ext_vector_type(4))) float f32x4;

static inline size_t ws_align(size_t x) { return (x + 511) & ~((size_t)511); }

static __device__ inline unsigned short f2bf(float f) {
    __hip_bfloat16 h = __float2bfloat16(f);
    return __builtin_bit_cast(unsigned short, h);
}

static __device__ inline float bf2f(unsigned short u) {
    unsigned int x = ((unsigned int)u) << 16;
    return __builtin_bit_cast(float, x);
}

// ---------------- GEMM block body for K1: 512 threads = 8 waves, 128 rows, W in LDS ----------------

static __device__ inline void gemm128_body(const void* __restrict__ Araw, int a_fp32,
                                           const void* __restrict__ Wraw, int w_fp32,
                                           unsigned short* __restrict__ out,
                                           int N, int blk) {
    constexpr int K = 128;
    constexpr int FOUT = 128;
    constexpr int NT = FOUT / 16;
    constexpr int LDB = K + 8;
    __shared__ __align__(16) unsigned short bt[FOUT * LDB];

    const int tid = threadIdx.x;  // 0..511
    const int base = blk * 128;

    constexpr int TOT4 = K * FOUT / 4;
    if (w_fp32) {
        const float* Wf = (const float*)Wraw;
        for (int i = tid; i < TOT4; i += 512) {
            int idx = i * 4;
            int k = idx / FOUT;
            int n = idx & (FOUT - 1);
            float4 v = *(const float4*)(const void*)(Wf + idx);
            bt[(n + 0) * LDB + k] = f2bf(v.x);
            bt[(n + 1) * LDB + k] = f2bf(v.y);
            bt[(n + 2) * LDB + k] = f2bf(v.z);
            bt[(n + 3) * LDB + k] = f2bf(v.w);
        }
    } else {
        const unsigned short* Ws = (const unsigned short*)Wraw;
        for (int i = tid; i < TOT4; i += 512) {
            int idx = i * 4;
            int k = idx / FOUT;
            int n = idx & (FOUT - 1);
            short4v v = *(const short4v*)(const void*)(Ws + idx);
#pragma unroll
            for (int j = 0; j < 4; j++) bt[(n + j) * LDB + k] = ((const unsigned short*)&v)[j];
        }
    }

    const int wave = tid >> 6;
    const int lane = tid & 63;
    const int quad = lane >> 4;
    const int r16 = lane & 15;

    int arow = base + wave * 16 + r16;
    if (arow > N - 1) arow = N - 1;

    short8 afrag[4];
    if (a_fp32) {
        const float* Ap = (const float*)Araw + (size_t)arow * K + quad * 8;
#pragma unroll
        for (int kk = 0; kk < 4; kk++) {
            float4 f0 = *(const float4*)(const void*)(Ap + kk * 32);
            float4 f1 = *(const float4*)(const void*)(Ap + kk * 32 + 4);
            short8 r;
            r[0] = (short)f2bf(f0.x); r[1] = (short)f2bf(f0.y);
            r[2] = (short)f2bf(f0.z); r[3] = (short)f2bf(f0.w);
            r[4] = (short)f2bf(f1.x); r[5] = (short)f2bf(f1.y);
            r[6] = (short)f2bf(f1.z); r[7] = (short)f2bf(f1.w);
            afrag[kk] = r;
        }
    } else {
        const unsigned short* Ap = (const unsigned short*)Araw + (size_t)arow * K + quad * 8;
#pragma unroll
        for (int kk = 0; kk < 4; kk++) afrag[kk] = *(const short8*)(const void*)(Ap + kk * 32);
    }

    __syncthreads();

    f32x4 acc[NT];
#pragma unroll
    for (int nt = 0; nt < NT; nt++) acc[nt] = (f32x4){0.f, 0.f, 0.f, 0.f};

#pragma unroll
    for (int kk = 0; kk < 4; kk++) {
#pragma unroll
        for (int nt = 0; nt < NT; nt++) {
            short8 b = *(const short8*)(const void*)(&bt[(nt * 16 + r16) * LDB + kk * 32 + quad * 8]);
            acc[nt] = __builtin_amdgcn_mfma_f32_16x16x32_bf16(afrag[kk], b, acc[nt], 0, 0, 0);
        }
    }

#pragma unroll
    for (int nt = 0; nt < NT; nt++) {
#pragma unroll
        for (int r = 0; r < 4; r++) {
            float v = acc[nt][r];
            float o = __shfl_xor(v, 1, 64);
            int row = base + wave * 16 + quad * 4 + r;
            if (((lane & 1) == 0) && row < N) {
                __hip_bfloat162 pk;
                pk.x = __float2bfloat16(v);
                pk.y = __float2bfloat16(o);
                *(__hip_bfloat162*)(out + (size_t)row * FOUT + nt * 16 + r16) = pk;
            }
        }
    }
}

// ---------------- K1: gemm1 (512-thr, 128-row blocks) || hist ----------------

__global__ __launch_bounds__(512) void gemm1_hist_kernel(const void* __restrict__ Xraw,
                                                         const unsigned short* __restrict__ w1s,
                                                         const int* __restrict__ ei,
                                                         int* __restrict__ counts,
                                                         int* __restrict__ loff,
                                                         int* __restrict__ flags,
                                                         unsigned short* __restrict__ out,
                                                         int N, int E, int gblocks) {
    const int tid = threadIdx.x;
    const int lane = tid & 63;

    unsigned ew = (w1s[2 * lane] >> 7) & 0xFF;
    unsigned long long m1 = __ballot(ew >= 100 && ew <= 130);
    const int in_fp32 = (__popcll(m1) < 48) ? 1 : 0;

    if (blockIdx.x >= gblocks) {
        unsigned long long m2 = __ballot(((const unsigned int*)ei)[2 * lane + 1] == 0u);
        const int ei64 = (__popcll(m2) >= 48) ? 1 : 0;
        if (blockIdx.x == gblocks && tid == 0) {
            flags[0] = in_fp32;
            flags[1] = ei64;
        }
        int e = (blockIdx.x - gblocks) * 512 + tid;
        if (e < E) {
            int d = ei64 ? ei[2 * (size_t)E + 2 * e] : ei[(size_t)E + e];
            loff[e] = atomicAdd(&counts[d], 1);
        }
        return;
    }

    gemm128_body(Xraw, in_fp32, (const void*)w1s, in_fp32, out, N, blockIdx.x);
}

// ---------------- CSR build (alloc + fill) ----------------

__global__ __launch_bounds__(256) void alloc_kernel(const int* __restrict__ counts,
                                                    float* __restrict__ dinv,
                                                    int* __restrict__ rowptr,
                                                    int* __restrict__ total, int N) {
    int n = blockIdx.x * blockDim.x + threadIdx.x;
    int lane = threadIdx.x & 63;
    int c = (n < N) ? counts[n] : 0;
    if (n < N) {
        int d = (c < 1) ? 1 : c;
        dinv[n] = rsqrtf((float)d);
    }
    int incl = c;
#pragma unroll
    for (int off = 1; off < 64; off <<= 1) {
        int v = __shfl_up(incl, off, 64);
        if (lane >= off) incl += v;
    }
    int wavetot = __shfl(incl, 63, 64);
    int base = 0;
    if (lane == 0) base = atomicAdd(total, wavetot);
    base = __shfl(base, 0, 64);
    if (n < N) rowptr[n] = base + incl - c;
}

__global__ void fill_kernel(const int* __restrict__ ei, const int* __restrict__ flags,
                            const float* __restrict__ dinv, const int* __restrict__ rowptr,
                            const int* __restrict__ loff, int2* __restrict__ edgedat, int E) {
    int e = blockIdx.x * blockDim.x + threadIdx.x;
    if (e < E) {
        int s, d;
        if (flags[1]) {
            s = ei[2 * e];
            d = ei[2 * (size_t)E + 2 * e];
        } else {
            s = ei[e];
            d = ei[(size_t)E + e];
        }
        int pos = rowptr[d] + loff[e];
        float wt = dinv[s] * dinv[d];
        edgedat[pos] = make_int2(s, __float_as_int(wt));
    }
}

// ---------------- Fused SpMM+GEMM: out = relu(agg(Hin)) @ W ----------------
// 1024 threads = 16 waves; wave w aggregates node blockIdx*16+w with the EXACT proven
// spmm128 inner loop (1 node/wave, full gather TLP). relu'd bf16 row -> agg LDS tile.
// Barrier. Waves 0..NT-1 each compute one 16x16 col-tile vs W staged in LDS.
// 39KB LDS -> 2 blocks/CU = 32 waves/CU.

template <int FOUT>
__global__ __launch_bounds__(1024, 8) void spmmgemm_kernel(const int2* __restrict__ edgedat,
                                                           const int* __restrict__ rowptr,
                                                           const int* __restrict__ counts,
                                                           const unsigned short* __restrict__ Hin,
                                                           const void* __restrict__ Wraw,
                                                           const int* __restrict__ flags,
                                                           unsigned short* __restrict__ out, int N) {
    constexpr int K = 128;
    constexpr int NT = FOUT / 16;
    constexpr int LDB = K + 8;
    constexpr int LDA = K + 8;
    __shared__ __align__(16) unsigned short bt[FOUT * LDB];
    __shared__ __align__(16) unsigned short agg[16 * LDA];

    const int tid = threadIdx.x;
    const int wave = tid >> 6;   // 0..15
    const int lane = tid & 63;
    const int w_fp32 = flags[0];

    // ---- stage W (transpose + optional convert), 1024 threads ----
    constexpr int TOT4 = K * FOUT / 4;
    if (w_fp32) {
        const float* Wf = (const float*)Wraw;
        for (int i = tid; i < TOT4; i += 1024) {
            int idx = i * 4;
            int k = idx / FOUT;
            int n = idx & (FOUT - 1);
            float4 v = *(const float4*)(const void*)(Wf + idx);
            bt[(n + 0) * LDB + k] = f2bf(v.x);
            bt[(n + 1) * LDB + k] = f2bf(v.y);
            bt[(n + 2) * LDB + k] = f2bf(v.z);
            bt[(n + 3) * LDB + k] = f2bf(v.w);
        }
    } else {
        const unsigned short* Ws = (const unsigned short*)Wraw;
        for (int i = tid; i < TOT4; i += 1024) {
            int idx = i * 4;
            int k = idx / FOUT;
            int n = idx & (FOUT - 1);
            short4v v = *(const short4v*)(const void*)(Ws + idx);
#pragma unroll
            for (int j = 0; j < 4; j++) bt[(n + j) * LDB + k] = ((const unsigned short*)&v)[j];
        }
    }

    // ---- gather phase: wave aggregates one node (proven spmm128 loop) ----
    const int grp = lane >> 4;
    const int gl = lane & 15;
    int node = blockIdx.x * 16 + wave;
    int start = 0, len = 0;
    if (node < N) {
        start = rowptr[node];
        len = counts[node];
    }
    start = __builtin_amdgcn_readfirstlane(start);
    len = __builtin_amdgcn_readfirstlane(len);
    const int2* ep = edgedat + start;

    float acc[8];
#pragma unroll
    for (int u = 0; u < 8; u++) acc[u] = 0.f;

    int j = 0;
    for (; j + 8 <= len; j += 8) {
        int2 e0 = ep[j + grp];
        int2 e1 = ep[j + 4 + grp];
        short8 h0 = *(const short8*)(const void*)(Hin + (size_t)e0.x * 128 + gl * 8);
        short8 h1 = *(const short8*)(const void*)(Hin + (size_t)e1.x * 128 + gl * 8);
        float w0 = __int_as_float(e0.y);
        float w1 = __int_as_float(e1.y);
#pragma unroll
        for (int u = 0; u < 8; u++) acc[u] += w0 * bf2f((unsigned short)h0[u]);
#pragma unroll
        for (int u = 0; u < 8; u++) acc[u] += w1 * bf2f((unsigned short)h1[u]);
    }
    for (; j + 4 <= len; j += 4) {
        int2 e = ep[j + grp];
        short8 h = *(const short8*)(const void*)(Hin + (size_t)e.x * 128 + gl * 8);
        float w = __int_as_float(e.y);
#pragma unroll
        for (int u = 0; u < 8; u++) acc[u] += w * bf2f((unsigned short)h[u]);
    }
    int rem = len - j;
    if (grp < rem) {
        int2 e = ep[j + grp];
        short8 h = *(const short8*)(const void*)(Hin + (size_t)e.x * 128 + gl * 8);
        float w = __int_as_float(e.y);
#pragma unroll
        for (int u = 0; u < 8; u++) acc[u] += w * bf2f((unsigned short)h[u]);
    }

#pragma unroll
    for (int u = 0; u < 8; u++) {
        acc[u] += __shfl_xor(acc[u], 16, 64);
        acc[u] += __shfl_xor(acc[u], 32, 64);
    }

    if (grp == 0) {
        short8 o;
#pragma unroll
        for (int u = 0; u < 8; u++) o[u] = (short)f2bf(fmaxf(acc[u], 0.f));  // relu between agg and GEMM
        *(short8*)(void*)(&agg[wave * LDA + gl * 8]) = o;
    }

    __syncthreads();

    // ---- MFMA phase: waves 0..NT-1, one col-tile each ----
    if (wave >= NT) return;
    const int quad = lane >> 4;
    const int r16 = lane & 15;

    short8 afrag[4];
#pragma unroll
    for (int kk = 0; kk < 4; kk++)
        afrag[kk] = *(const short8*)(const void*)(&agg[r16 * LDA + kk * 32 + quad * 8]);

    f32x4 c = (f32x4){0.f, 0.f, 0.f, 0.f};
#pragma unroll
    for (int kk = 0; kk < 4; kk++) {
        short8 b = *(const short8*)(const void*)(&bt[(wave * 16 + r16) * LDB + kk * 32 + quad * 8]);
        c = __builtin_amdgcn_mfma_f32_16x16x32_bf16(afrag[kk], b, c, 0, 0, 0);
    }

#pragma unroll
    for (int r = 0; r < 4; r++) {
        float v = c[r];
        float o = __shfl_xor(v, 1, 64);
        int row = blockIdx.x * 16 + quad * 4 + r;
        if (((lane & 1) == 0) && row < N) {
            __hip_bfloat162 pk;
            pk.x = __float2bfloat16(v);
            pk.y = __float2bfloat16(o);
            *(__hip_bfloat162*)(out + (size_t)row * FOUT + wave * 16 + r16) = pk;
        }
    }
}

// ---------------- SpMM F=64 + relu + softmax: 8 edges in flight (8-lane groups) ----------------

__global__ __launch_bounds__(256) void spmm64_softmax_kernel(const int2* __restrict__ edgedat,
                                                             const int* __restrict__ rowptr,
                                                             const int* __restrict__ counts,
                                                             const unsigned short* __restrict__ Hin,
                                                             const int* __restrict__ flags,
                                                             void* __restrict__ Out, int N) {
    int wid = (blockIdx.x * 256 + threadIdx.x) >> 6;
    if (wid >= N) return;
    int lane = threadIdx.x & 63;
    int grp = lane >> 3;
    int gl = lane & 7;
    int n = __builtin_amdgcn_readfirstlane(wid);
    int start = __builtin_amdgcn_readfirstlane(rowptr[n]);
    int len = __builtin_amdgcn_readfirstlane(counts[n]);
    const int2* ep = edgedat + start;

    float acc[8];
#pragma unroll
    for (int u = 0; u < 8; u++) acc[u] = 0.f;

    int j = 0;
    for (; j + 16 <= len; j += 16) {
        int2 e0 = ep[j + grp];
        int2 e1 = ep[j + 8 + grp];
        short8 h0 = *(const short8*)(const void*)(Hin + (size_t)e0.x * 64 + gl * 8);
        short8 h1 = *(const short8*)(const void*)(Hin + (size_t)e1.x * 64 + gl * 8);
        float w0 = __int_as_float(e0.y);
        float w1 = __int_as_float(e1.y);
#pragma unroll
        for (int u = 0; u < 8; u++) acc[u] += w0 * bf2f((unsigned short)h0[u]);
#pragma unroll
        for (int u = 0; u < 8; u++) acc[u] += w1 * bf2f((unsigned short)h1[u]);
    }
    for (; j + 8 <= len; j += 8) {
        int2 e = ep[j + grp];
        short8 h = *(const short8*)(const void*)(Hin + (size_t)e.x * 64 + gl * 8);
        float w = __int_as_float(e.y);
#pragma unroll
        for (int u = 0; u < 8; u++) acc[u] += w * bf2f((unsigned short)h[u]);
    }
    int rem = len - j;
    if (grp < rem) {
        int2 e = ep[j + grp];
        short8 h = *(const short8*)(const void*)(Hin + (size_t)e.x * 64 + gl * 8);
        float w = __int_as_float(e.y);
#pragma unroll
        for (int u = 0; u < 8; u++) acc[u] += w * bf2f((unsigned short)h[u]);
    }

#pragma unroll
    for (int u = 0; u < 8; u++) {
        acc[u] += __shfl_xor(acc[u], 8, 64);
        acc[u] += __shfl_xor(acc[u], 16, 64);
        acc[u] += __shfl_xor(acc[u], 32, 64);
    }

#pragma unroll
    for (int u = 0; u < 8; u++) acc[u] = fmaxf(acc[u], 0.f);

    float m = acc[0];
#pragma unroll
    for (int u = 1; u < 8; u++) m = fmaxf(m, acc[u]);
#pragma unroll
    for (int off = 1; off < 8; off <<= 1) m = fmaxf(m, __shfl_xor(m, off, 64));

    float ex[8];
    float s = 0.f;
#pragma unroll
    for (int u = 0; u < 8; u++) {
        ex[u] = __expf(acc[u] - m);
        s += ex[u];
    }
#pragma unroll
    for (int off = 1; off < 8; off <<= 1) s += __shfl_xor(s, off, 64);
    float inv = 1.0f / s;

    if (grp == 0) {
        if (flags[0]) {
            float* op = (float*)Out + (size_t)n * 64 + gl * 8;
            float4 v0, v1;
            v0.x = ex[0] * inv; v0.y = ex[1] * inv; v0.z = ex[2] * inv; v0.w = ex[3] * inv;
            v1.x = ex[4] * inv; v1.y = ex[5] * inv; v1.z = ex[6] * inv; v1.w = ex[7] * inv;
            *(float4*)(void*)op = v0;
            *(float4*)(void*)(op + 4) = v1;
        } else {
            short8 o;
#pragma unroll
            for (int u = 0; u < 8; u++) o[u] = (short)f2bf(ex[u] * inv);
            *(short8*)(void*)((unsigned short*)Out + (size_t)n * 64 + gl * 8) = o;
        }
    }
}

// ---------------- launch ----------------

extern "C" void kernel_launch(void* const* d_in, const int* in_sizes, int n_in,
                              void* d_out, int out_size, void* d_ws, size_t ws_size,
                              hipStream_t stream) {
    const void* X  = d_in[0];                       // [N,128] bf16 or fp32
    const int*  ei = (const int*)d_in[1];           // [2,E] int32 or int64
    const void* W1 = d_in[2];                       // [128,128]
    const void* W2 = d_in[3];                       // [128,128]
    const void* W3 = d_in[4];                       // [128,64]

    const int N = in_sizes[0] / 128;   // 50000
    const int E = in_sizes[1] / 2;     // 800000

    char* ws = (char*)d_ws;
    size_t off = 0;
    int* counts = (int*)(ws + off);   off += ws_align((size_t)N * 4);
    int* total  = (int*)(ws + off);   off += ws_align(64);
    const size_t zero_bytes = off;    // counts + total need zeroing
    int* flags    = (int*)(ws + off);   off += ws_align(64);
    int* rowptr   = (int*)(ws + off);   off += ws_align((size_t)N * 4);
    float* dinv   = (float*)(ws + off); off += ws_align((size_t)N * 4);
    int* loff     = (int*)(ws + off);   off += ws_align((size_t)E * 4);
    int2* edgedat = (int2*)(ws + off);  off += ws_align((size_t)E * 8);
    unsigned short* HA = (unsigned short*)(ws + off); off += ws_align((size_t)N * 128 * 2);
    unsigned short* HB = (unsigned short*)(ws + off); off += ws_align((size_t)N * 128 * 2);

    hipMemsetAsync(d_ws, 0, zero_bytes, stream);

    const int gblocks = (N + 127) / 128;       // 391
    const int hblocks = (E + 511) / 512;       // 1563
    const int fblocks = (N + 15) / 16;         // 3125
    const int sblocks = (N * 64 + 255) / 256;  // 12500

    // K1: gemm1 (X @ W1 -> HA) || hist + flag publish
    gemm1_hist_kernel<<<gblocks + hblocks, 512, 0, stream>>>(
        X, (const unsigned short*)W1, ei, counts, loff, flags, HA, N, E, gblocks);
    alloc_kernel<<<(N + 255) / 256, 256, 0, stream>>>(counts, dinv, rowptr, total, N);
    fill_kernel<<<(E + 255) / 256, 256, 0, stream>>>(ei, flags, dinv, rowptr, loff, edgedat, E);

    // F1: HB = relu(agg(HA)) @ W2   (h1 never materializes)
    spmmgemm_kernel<128><<<fblocks, 1024, 0, stream>>>(edgedat, rowptr, counts, HA, W2, flags, HB, N);
    // F2: HA = relu(agg(HB)) @ W3
    spmmgemm_kernel<64><<<fblocks, 1024, 0, stream>>>(edgedat, rowptr, counts, HB, W3, flags, HA, N);
    // final: out = softmax(relu(agg(HA)))
    spmm64_softmax_kernel<<<sblocks, 256, 0, stream>>>(edgedat, rowptr, counts, HA, flags, d_out, N);
}

// Round 12
// 254.987 us; speedup vs baseline: 1.1170x; 1.1170x over previous
//
#include <hip/hip_runtime.h>
#include <hip/hip_bf16.h>

typedef __attribute__((ext_vector_type(8))) short short8;
typedef __attribute__((ext_vector_type(4))) short short4v;
typedef __attribute__((ext_vector_type(4))) float f32x4;

static inline size_t ws_align(size_t x) { return (x + 511) & ~((size_t)511); }

static __device__ inline unsigned short f2bf(float f) {
    __hip_bfloat16 h = __float2bfloat16(f);
    return __builtin_bit_cast(unsigned short, h);
}

static __device__ inline float bf2f(unsigned short u) {
    unsigned int x = ((unsigned int)u) << 16;
    return __builtin_bit_cast(float, x);
}

// ---------------- K1: gemm1 (X @ W1, LDS-staged) || hist, fused ----------------
// Blocks [0, gblocks): gemm1. Blocks [gblocks, gblocks+hblocks): hist + flag write.
// dtype flags computed wave-locally via ballot (no cross-block dependency).

__global__ __launch_bounds__(256) void gemm1_hist_kernel(const void* __restrict__ Araw,
                                                         const unsigned short* __restrict__ w1s,
                                                         const int* __restrict__ ei,
                                                         int* __restrict__ counts,
                                                         int* __restrict__ loff,
                                                         int* __restrict__ flags,
                                                         unsigned short* __restrict__ out,
                                                         int Nrows, int E, int gblocks) {
    constexpr int K = 128;
    constexpr int FOUT = 128;
    constexpr int NT = FOUT / 16;
    constexpr int LDB = K + 8;
    __shared__ __align__(16) unsigned short bt[FOUT * LDB];

    const int tid = threadIdx.x;
    const int lane = tid & 63;

    // wave-local dtype sniff (uniform across waves; cheap, L2-hot)
    unsigned ew = (w1s[2 * lane] >> 7) & 0xFF;
    unsigned long long m1 = __ballot(ew >= 100 && ew <= 130);
    const int in_fp32 = (__popcll(m1) < 48) ? 1 : 0;
    unsigned long long m2 = __ballot(((const unsigned int*)ei)[2 * lane + 1] == 0u);
    const int ei64 = (__popcll(m2) >= 48) ? 1 : 0;

    if (blockIdx.x >= gblocks) {
        // ---- hist part ----
        if (blockIdx.x == gblocks && tid == 0) {
            flags[0] = in_fp32;
            flags[1] = ei64;
        }
        int e = (blockIdx.x - gblocks) * 256 + tid;
        if (e < E) {
            int d = ei64 ? ei[2 * (size_t)E + 2 * e] : ei[(size_t)E + e];
            loff[e] = atomicAdd(&counts[d], 1);
        }
        return;
    }

    // ---- gemm1 part: stage W1 -> bt[n][k] ----
    constexpr int TOT4 = K * FOUT / 4;
    if (in_fp32) {
        const float* Wf = (const float*)(const void*)w1s;
        for (int i = tid; i < TOT4; i += 256) {
            int idx = i * 4;
            int k = idx / FOUT;
            int n = idx & (FOUT - 1);
            float4 v = *(const float4*)(const void*)(Wf + idx);
            bt[(n + 0) * LDB + k] = f2bf(v.x);
            bt[(n + 1) * LDB + k] = f2bf(v.y);
            bt[(n + 2) * LDB + k] = f2bf(v.z);
            bt[(n + 3) * LDB + k] = f2bf(v.w);
        }
    } else {
        for (int i = tid; i < TOT4; i += 256) {
            int idx = i * 4;
            int k = idx / FOUT;
            int n = idx & (FOUT - 1);
            short4v v = *(const short4v*)(const void*)(w1s + idx);
#pragma unroll
            for (int j = 0; j < 4; j++) bt[(n + j) * LDB + k] = ((const unsigned short*)&v)[j];
        }
    }

    const int wave = tid >> 6;
    const int quad = lane >> 4;
    const int r16 = lane & 15;

    short8 afrag[2][4];
#pragma unroll
    for (int t = 0; t < 2; t++) {
        int arow = blockIdx.x * 128 + t * 64 + wave * 16 + r16;
        if (arow > Nrows - 1) arow = Nrows - 1;
        if (in_fp32) {
            const float* Ap = (const float*)Araw + (size_t)arow * K + quad * 8;
#pragma unroll
            for (int kk = 0; kk < 4; kk++) {
                float4 f0 = *(const float4*)(const void*)(Ap + kk * 32);
                float4 f1 = *(const float4*)(const void*)(Ap + kk * 32 + 4);
                short8 r;
                r[0] = (short)f2bf(f0.x); r[1] = (short)f2bf(f0.y);
                r[2] = (short)f2bf(f0.z); r[3] = (short)f2bf(f0.w);
                r[4] = (short)f2bf(f1.x); r[5] = (short)f2bf(f1.y);
                r[6] = (short)f2bf(f1.z); r[7] = (short)f2bf(f1.w);
                afrag[t][kk] = r;
            }
        } else {
            const unsigned short* Ap = (const unsigned short*)Araw + (size_t)arow * K + quad * 8;
#pragma unroll
            for (int kk = 0; kk < 4; kk++) afrag[t][kk] = *(const short8*)(const void*)(Ap + kk * 32);
        }
    }

    __syncthreads();

    f32x4 acc[2][NT];
#pragma unroll
    for (int t = 0; t < 2; t++)
#pragma unroll
        for (int nt = 0; nt < NT; nt++) acc[t][nt] = (f32x4){0.f, 0.f, 0.f, 0.f};

#pragma unroll
    for (int kk = 0; kk < 4; kk++) {
#pragma unroll
        for (int nt = 0; nt < NT; nt++) {
            short8 b = *(const short8*)(const void*)(&bt[(nt * 16 + r16) * LDB + kk * 32 + quad * 8]);
#pragma unroll
            for (int t = 0; t < 2; t++)
                acc[t][nt] = __builtin_amdgcn_mfma_f32_16x16x32_bf16(afrag[t][kk], b, acc[t][nt], 0, 0, 0);
        }
    }

#pragma unroll
    for (int t = 0; t < 2; t++) {
#pragma unroll
        for (int nt = 0; nt < NT; nt++) {
#pragma unroll
            for (int r = 0; r < 4; r++) {
                float v = acc[t][nt][r];
                float o = __shfl_xor(v, 1, 64);
                int row = blockIdx.x * 128 + t * 64 + wave * 16 + quad * 4 + r;
                if (((lane & 1) == 0) && row < Nrows) {
                    __hip_bfloat162 pk;
                    pk.x = __float2bfloat16(v);
                    pk.y = __float2bfloat16(o);
                    *(__hip_bfloat162*)(out + (size_t)row * FOUT + nt * 16 + r16) = pk;
                }
            }
        }
    }
}

// ---------------- CSR build (alloc + fill) ----------------

__global__ __launch_bounds__(256) void alloc_kernel(const int* __restrict__ counts,
                                                    float* __restrict__ dinv,
                                                    int* __restrict__ rowptr,
                                                    int* __restrict__ total, int N) {
    int n = blockIdx.x * blockDim.x + threadIdx.x;
    int lane = threadIdx.x & 63;
    int c = (n < N) ? counts[n] : 0;
    if (n < N) {
        int d = (c < 1) ? 1 : c;
        dinv[n] = rsqrtf((float)d);
    }
    int incl = c;
#pragma unroll
    for (int off = 1; off < 64; off <<= 1) {
        int v = __shfl_up(incl, off, 64);
        if (lane >= off) incl += v;
    }
    int wavetot = __shfl(incl, 63, 64);
    int base = 0;
    if (lane == 0) base = atomicAdd(total, wavetot);
    base = __shfl(base, 0, 64);
    if (n < N) rowptr[n] = base + incl - c;
}

__global__ void fill_kernel(const int* __restrict__ ei, const int* __restrict__ flags,
                            const float* __restrict__ dinv, const int* __restrict__ rowptr,
                            const int* __restrict__ loff, int2* __restrict__ edgedat, int E) {
    int e = blockIdx.x * blockDim.x + threadIdx.x;
    if (e < E) {
        int s, d;
        if (flags[1]) {
            s = ei[2 * e];
            d = ei[2 * (size_t)E + 2 * e];
        } else {
            s = ei[e];
            d = ei[(size_t)E + e];
        }
        int pos = rowptr[d] + loff[e];
        float wt = dinv[s] * dinv[d];
        edgedat[pos] = make_int2(s, __float_as_int(wt));
    }
}

// ---------------- GEMM (layers 2,3): out[N x FOUT] = A[N x 128] @ W, LDS-staged W ----------------

template <int FOUT>
__global__ __launch_bounds__(256) void gemm_kernel(const void* __restrict__ Araw,
                                                   const void* __restrict__ Wraw,
                                                   const int* __restrict__ flags,
                                                   unsigned short* __restrict__ out, int Nrows) {
    constexpr int K = 128;
    constexpr int NT = FOUT / 16;
    constexpr int LDB = K + 8;
    __shared__ __align__(16) unsigned short bt[FOUT * LDB];

    const int tid = threadIdx.x;
    const int in_fp32 = flags[0];

    constexpr int TOT4 = K * FOUT / 4;
    if (in_fp32) {
        const float* Wf = (const float*)Wraw;
        for (int i = tid; i < TOT4; i += 256) {
            int idx = i * 4;
            int k = idx / FOUT;
            int n = idx & (FOUT - 1);
            float4 v = *(const float4*)(const void*)(Wf + idx);
            bt[(n + 0) * LDB + k] = f2bf(v.x);
            bt[(n + 1) * LDB + k] = f2bf(v.y);
            bt[(n + 2) * LDB + k] = f2bf(v.z);
            bt[(n + 3) * LDB + k] = f2bf(v.w);
        }
    } else {
        const unsigned short* Ws = (const unsigned short*)Wraw;
        for (int i = tid; i < TOT4; i += 256) {
            int idx = i * 4;
            int k = idx / FOUT;
            int n = idx & (FOUT - 1);
            short4v v = *(const short4v*)(const void*)(Ws + idx);
#pragma unroll
            for (int j = 0; j < 4; j++) bt[(n + j) * LDB + k] = ((const unsigned short*)&v)[j];
        }
    }

    const int wave = tid >> 6;
    const int lane = tid & 63;
    const int quad = lane >> 4;
    const int r16 = lane & 15;

    // A is internal bf16 [N][128]
    short8 afrag[2][4];
#pragma unroll
    for (int t = 0; t < 2; t++) {
        int arow = blockIdx.x * 128 + t * 64 + wave * 16 + r16;
        if (arow > Nrows - 1) arow = Nrows - 1;
        const unsigned short* Ap = (const unsigned short*)Araw + (size_t)arow * K + quad * 8;
#pragma unroll
        for (int kk = 0; kk < 4; kk++) afrag[t][kk] = *(const short8*)(const void*)(Ap + kk * 32);
    }

    __syncthreads();

    f32x4 acc[2][NT];
#pragma unroll
    for (int t = 0; t < 2; t++)
#pragma unroll
        for (int nt = 0; nt < NT; nt++) acc[t][nt] = (f32x4){0.f, 0.f, 0.f, 0.f};

#pragma unroll
    for (int kk = 0; kk < 4; kk++) {
#pragma unroll
        for (int nt = 0; nt < NT; nt++) {
            short8 b = *(const short8*)(const void*)(&bt[(nt * 16 + r16) * LDB + kk * 32 + quad * 8]);
#pragma unroll
            for (int t = 0; t < 2; t++)
                acc[t][nt] = __builtin_amdgcn_mfma_f32_16x16x32_bf16(afrag[t][kk], b, acc[t][nt], 0, 0, 0);
        }
    }

#pragma unroll
    for (int t = 0; t < 2; t++) {
#pragma unroll
        for (int nt = 0; nt < NT; nt++) {
#pragma unroll
            for (int r = 0; r < 4; r++) {
                float v = acc[t][nt][r];
                float o = __shfl_xor(v, 1, 64);
                int row = blockIdx.x * 128 + t * 64 + wave * 16 + quad * 4 + r;
                if (((lane & 1) == 0) && row < Nrows) {
                    __hip_bfloat162 pk;
                    pk.x = __float2bfloat16(v);
                    pk.y = __float2bfloat16(o);
                    *(__hip_bfloat162*)(out + (size_t)row * FOUT + nt * 16 + r16) = pk;
                }
            }
        }
    }
}

// ---------------- SpMM: wave per node, 4 edges in flight (16-lane groups, 16B row slices) ----------------

__global__ __launch_bounds__(256) void spmm128_kernel(const int2* __restrict__ edgedat,
                                                      const int* __restrict__ rowptr,
                                                      const int* __restrict__ counts,
                                                      const unsigned short* __restrict__ Hin,
                                                      unsigned short* __restrict__ Hout, int N) {
    int wid = (blockIdx.x * 256 + threadIdx.x) >> 6;
    if (wid >= N) return;
    int lane = threadIdx.x & 63;
    int grp = lane >> 4;
    int gl = lane & 15;
    int n = __builtin_amdgcn_readfirstlane(wid);
    int start = __builtin_amdgcn_readfirstlane(rowptr[n]);
    int len = __builtin_amdgcn_readfirstlane(counts[n]);
    const int2* ep = edgedat + start;

    float acc[8];
#pragma unroll
    for (int u = 0; u < 8; u++) acc[u] = 0.f;

    int j = 0;
    for (; j + 8 <= len; j += 8) {
        int2 e0 = ep[j + grp];
        int2 e1 = ep[j + 4 + grp];
        short8 h0 = *(const short8*)(const void*)(Hin + (size_t)e0.x * 128 + gl * 8);
        short8 h1 = *(const short8*)(const void*)(Hin + (size_t)e1.x * 128 + gl * 8);
        float w0 = __int_as_float(e0.y);
        float w1 = __int_as_float(e1.y);
#pragma unroll
        for (int u = 0; u < 8; u++) acc[u] += w0 * bf2f((unsigned short)h0[u]);
#pragma unroll
        for (int u = 0; u < 8; u++) acc[u] += w1 * bf2f((unsigned short)h1[u]);
    }
    for (; j + 4 <= len; j += 4) {
        int2 e = ep[j + grp];
        short8 h = *(const short8*)(const void*)(Hin + (size_t)e.x * 128 + gl * 8);
        float w = __int_as_float(e.y);
#pragma unroll
        for (int u = 0; u < 8; u++) acc[u] += w * bf2f((unsigned short)h[u]);
    }
    int rem = len - j;
    if (grp < rem) {
        int2 e = ep[j + grp];
        short8 h = *(const short8*)(const void*)(Hin + (size_t)e.x * 128 + gl * 8);
        float w = __int_as_float(e.y);
#pragma unroll
        for (int u = 0; u < 8; u++) acc[u] += w * bf2f((unsigned short)h[u]);
    }

#pragma unroll
    for (int u = 0; u < 8; u++) {
        acc[u] += __shfl_xor(acc[u], 16, 64);
        acc[u] += __shfl_xor(acc[u], 32, 64);
    }

    if (grp == 0) {
        short8 o;
#pragma unroll
        for (int u = 0; u < 8; u++) o[u] = (short)f2bf(fmaxf(acc[u], 0.f));
        *(short8*)(void*)(Hout + (size_t)n * 128 + gl * 8) = o;
    }
}

// ---------------- SpMM F=64 + relu + softmax: 8 edges in flight (8-lane groups) ----------------

__global__ __launch_bounds__(256) void spmm64_softmax_kernel(const int2* __restrict__ edgedat,
                                                             const int* __restrict__ rowptr,
                                                             const int* __restrict__ counts,
                                                             const unsigned short* __restrict__ Hin,
                                                             const int* __restrict__ flags,
                                                             void* __restrict__ Out, int N) {
    int wid = (blockIdx.x * 256 + threadIdx.x) >> 6;
    if (wid >= N) return;
    int lane = threadIdx.x & 63;
    int grp = lane >> 3;
    int gl = lane & 7;
    int n = __builtin_amdgcn_readfirstlane(wid);
    int start = __builtin_amdgcn_readfirstlane(rowptr[n]);
    int len = __builtin_amdgcn_readfirstlane(counts[n]);
    const int2* ep = edgedat + start;

    float acc[8];
#pragma unroll
    for (int u = 0; u < 8; u++) acc[u] = 0.f;

    int j = 0;
    for (; j + 16 <= len; j += 16) {
        int2 e0 = ep[j + grp];
        int2 e1 = ep[j + 8 + grp];
        short8 h0 = *(const short8*)(const void*)(Hin + (size_t)e0.x * 64 + gl * 8);
        short8 h1 = *(const short8*)(const void*)(Hin + (size_t)e1.x * 64 + gl * 8);
        float w0 = __int_as_float(e0.y);
        float w1 = __int_as_float(e1.y);
#pragma unroll
        for (int u = 0; u < 8; u++) acc[u] += w0 * bf2f((unsigned short)h0[u]);
#pragma unroll
        for (int u = 0; u < 8; u++) acc[u] += w1 * bf2f((unsigned short)h1[u]);
    }
    for (; j + 8 <= len; j += 8) {
        int2 e = ep[j + grp];
        short8 h = *(const short8*)(const void*)(Hin + (size_t)e.x * 64 + gl * 8);
        float w = __int_as_float(e.y);
#pragma unroll
        for (int u = 0; u < 8; u++) acc[u] += w * bf2f((unsigned short)h[u]);
    }
    int rem = len - j;
    if (grp < rem) {
        int2 e = ep[j + grp];
        short8 h = *(const short8*)(const void*)(Hin + (size_t)e.x * 64 + gl * 8);
        float w = __int_as_float(e.y);
#pragma unroll
        for (int u = 0; u < 8; u++) acc[u] += w * bf2f((unsigned short)h[u]);
    }

#pragma unroll
    for (int u = 0; u < 8; u++) {
        acc[u] += __shfl_xor(acc[u], 8, 64);
        acc[u] += __shfl_xor(acc[u], 16, 64);
        acc[u] += __shfl_xor(acc[u], 32, 64);
    }

#pragma unroll
    for (int u = 0; u < 8; u++) acc[u] = fmaxf(acc[u], 0.f);

    float m = acc[0];
#pragma unroll
    for (int u = 1; u < 8; u++) m = fmaxf(m, acc[u]);
#pragma unroll
    for (int off = 1; off < 8; off <<= 1) m = fmaxf(m, __shfl_xor(m, off, 64));

    float ex[8];
    float s = 0.f;
#pragma unroll
    for (int u = 0; u < 8; u++) {
        ex[u] = __expf(acc[u] - m);
        s += ex[u];
    }
#pragma unroll
    for (int off = 1; off < 8; off <<= 1) s += __shfl_xor(s, off, 64);
    float inv = 1.0f / s;

    if (grp == 0) {
        if (flags[0]) {
            float* op = (float*)Out + (size_t)n * 64 + gl * 8;
            float4 v0, v1;
            v0.x = ex[0] * inv; v0.y = ex[1] * inv; v0.z = ex[2] * inv; v0.w = ex[3] * inv;
            v1.x = ex[4] * inv; v1.y = ex[5] * inv; v1.z = ex[6] * inv; v1.w = ex[7] * inv;
            *(float4*)(void*)op = v0;
            *(float4*)(void*)(op + 4) = v1;
        } else {
            short8 o;
#pragma unroll
            for (int u = 0; u < 8; u++) o[u] = (short)f2bf(ex[u] * inv);
            *(short8*)(void*)((unsigned short*)Out + (size_t)n * 64 + gl * 8) = o;
        }
    }
}

// ---------------- launch ----------------

extern "C" void kernel_launch(void* const* d_in, const int* in_sizes, int n_in,
                              void* d_out, int out_size, void* d_ws, size_t ws_size,
                              hipStream_t stream) {
    const void* X  = d_in[0];                       // [N,128] bf16 or fp32
    const int*  ei = (const int*)d_in[1];           // [2,E] int32 or int64
    const void* W1 = d_in[2];                       // [128,128]
    const void* W2 = d_in[3];                       // [128,128]
    const void* W3 = d_in[4];                       // [128,64]

    const int N = in_sizes[0] / 128;   // 50000
    const int E = in_sizes[1] / 2;     // 800000

    char* ws = (char*)d_ws;
    size_t off = 0;
    int* counts = (int*)(ws + off);   off += ws_align((size_t)N * 4);
    int* total  = (int*)(ws + off);   off += ws_align(64);
    const size_t zero_bytes = off;    // counts + total need zeroing
    int* flags    = (int*)(ws + off);   off += ws_align(64);
    int* rowptr   = (int*)(ws + off);   off += ws_align((size_t)N * 4);
    float* dinv   = (float*)(ws + off); off += ws_align((size_t)N * 4);
    int* loff     = (int*)(ws + off);   off += ws_align((size_t)E * 4);
    int2* edgedat = (int2*)(ws + off);  off += ws_align((size_t)E * 8);
    unsigned short* HA = (unsigned short*)(ws + off); off += ws_align((size_t)N * 128 * 2);
    unsigned short* HB = (unsigned short*)(ws + off); off += ws_align((size_t)N * 128 * 2);

    hipMemsetAsync(d_ws, 0, zero_bytes, stream);

    const int gblocks = (N + 127) / 128;       // 391
    const int hblocks = (E + 255) / 256;       // 3125
    const int sblocks = (N * 64 + 255) / 256;

    // K1: gemm1 (X @ W1 -> HA) in parallel with hist (counts/loff) + flag write
    gemm1_hist_kernel<<<gblocks + hblocks, 256, 0, stream>>>(
        X, (const unsigned short*)W1, ei, counts, loff, flags, HA, N, E, gblocks);
    alloc_kernel<<<(N + 255) / 256, 256, 0, stream>>>(counts, dinv, rowptr, total, N);
    fill_kernel<<<hblocks, 256, 0, stream>>>(ei, flags, dinv, rowptr, loff, edgedat, E);

    // layer 1 aggregate: HB = relu(A_norm HA)
    spmm128_kernel<<<sblocks, 256, 0, stream>>>(edgedat, rowptr, counts, HA, HB, N);
    // layer 2
    gemm_kernel<128><<<gblocks, 256, 0, stream>>>(HB, W2, flags, HA, N);
    spmm128_kernel<<<sblocks, 256, 0, stream>>>(edgedat, rowptr, counts, HA, HB, N);
    // layer 3 (F_out = 64) + relu + softmax
    gemm_kernel<64><<<gblocks, 256, 0, stream>>>(HB, W3, flags, HA, N);
    spmm64_softmax_kernel<<<sblocks, 256, 0, stream>>>(edgedat, rowptr, counts, HA, flags, d_out, N);
}